// Round 1
// baseline (316.994 us; speedup 1.0000x reference)
//
#include <hip/hip_runtime.h>

#define NBATCH 32
#define NN     1024     // d_model = number of nodes
#define NF     128      // win_size = node feature dim
#define NDG    64       // graph embed dim
#define TOPK   15

// ---------------- workspace layout (bytes) ----------------
#define OFF_QH    ((size_t)0)            // bf16-hi q [32][1024][64]  4 MiB
#define OFF_QL    ((size_t)4194304)      // bf16-lo q                 4 MiB
#define OFF_KH    ((size_t)8388608)      // bf16-hi k                 4 MiB
#define OFF_KL    ((size_t)12582912)     // bf16-lo k                 4 MiB
#define OFF_H     ((size_t)16777216)     // f32 [32][1024][128]      16 MiB
#define OFF_DEG   ((size_t)33554432)     // i32 [32][1024]          128 KiB
#define OFF_BMP   ((size_t)33685504)     // u32 [32][1024][32]        4 MiB
#define OFF_WL    ((size_t)37879808)     // wl_cnt + wl[32767]      128 KiB
#define OFF_TOPK  ((size_t)38010880)     // i32 [32][1024][16]        2 MiB
#define OFF_W64   ((size_t)40108032)     // f64 Wq64[8192], Wk64[8192] 128 KiB
#define OFF_QT64  ((size_t)40239104)     // f64 [32][64][1024]       16 MiB
#define OFF_KT64  ((size_t)57016320)     // f64 [32][64][1024]       16 MiB
#define OFF_TMP   ((size_t)0)            // f32 [32][1024][128]      16 MiB (overlaps QH..KL, dead by then)

typedef short s8v  __attribute__((ext_vector_type(8)));   // 8 bf16 (4 VGPRs) MFMA operand
typedef float f4v  __attribute__((ext_vector_type(4)));   // MFMA accumulator
typedef unsigned short us8v __attribute__((ext_vector_type(8)));

__device__ inline unsigned short bf16_rne(float f) {
    unsigned u = __float_as_uint(f);
    return (unsigned short)((u + 0x7FFFu + ((u >> 16) & 1u)) >> 16);
}
__device__ inline float bf16_tof(unsigned short h) { return __uint_as_float(((unsigned)h) << 16); }

// monotone 22-bit code for f32 score in window [-4, 4): sign + 5-bit biased exp + 16-bit mantissa
__device__ inline unsigned pack22(float s) {
    unsigned u   = __float_as_uint(s);
    int      mag = (int)(u & 0x7FFFFFFFu);
    int      t   = mag - 0x38800000;                 // bias at 2^-14
    t = t < 0 ? 0 : (t > 0x07FFFFFF ? 0x07FFFFFF : t);
    unsigned ts = (unsigned)t >> 6;                  // 21 bits
    return ((int)u < 0) ? (0x1FFFFFu - ts) : (0x200000u | ts);
}
__device__ inline float dec22(unsigned val22) {
    bool pos = (val22 & 0x200000u) != 0;
    unsigned ts = pos ? (val22 & 0x1FFFFFu) : (0x1FFFFFu - (val22 & 0x1FFFFFu));
    float f = __uint_as_float((ts << 6) + 0x38800000u);
    return pos ? f : -f;
}

__global__ __launch_bounds__(256) void k_upcast(const float* __restrict__ Wq,
                                                const float* __restrict__ Wk,
                                                double* __restrict__ Wq64,
                                                double* __restrict__ Wk64) {
    int i = blockIdx.x * 256 + threadIdx.x;  // 0..8191
    Wq64[i] = (double)Wq[i];
    Wk64[i] = (double)Wk[i];
}

// Fused: zero deg/bmp/wl_cnt + q,k f64 (repair path) + bf16 hi/lo splits + h = nf@Wg.T.
// grid (16 node-tiles, 2 halves, 32 batch), block 256. lane = node within 64-node tile.
__global__ __launch_bounds__(256) void k_prep(
    const float* __restrict__ x, const float* __restrict__ bq, const float* __restrict__ bk,
    const double* __restrict__ Wq64, const double* __restrict__ Wk64,
    const float* __restrict__ Wg,
    unsigned short* __restrict__ qh, unsigned short* __restrict__ ql,
    unsigned short* __restrict__ kh, unsigned short* __restrict__ kl,
    double* __restrict__ qT64, double* __restrict__ kT64,
    float* __restrict__ h,
    uint4* __restrict__ zbase, int zn)
{
    __shared__ float xs[64 * 129];   // xs[node][f], pad 129 -> conflict-free
    const int t = threadIdx.x;
    const int l = t & 63;
    const int w = t >> 6;
    const int uw = __builtin_amdgcn_readfirstlane(w);
    const int n0 = blockIdx.x * 64;
    const int half = blockIdx.y;
    const int b  = blockIdx.z;

    // --- zero phase (deg + bmp + wl_cnt), grid-stride over 1024 blocks ---
    {
        int lid = ((b * 2 + half) * 16 + blockIdx.x) * 256 + t;   // 0..262143
        for (int i = lid; i < zn; i += 262144)
            zbase[i] = make_uint4(0u, 0u, 0u, 0u);
    }

    {   // xs[node][f] = x[b][f][n0+node]  (coalesced over node)
        const int j = t & 63, fg = t >> 6;
        for (int ff = 0; ff < 32; ++ff) {
            int f = fg + ff * 4;
            xs[j * 129 + f] = x[((size_t)b * NF + f) * NN + n0 + j];
        }
    }
    __syncthreads();

    // --- q/k phase (f64, 8 d-dims per wave) ---
    {
        const int d0 = half * 32 + uw * 8;
        double accq[8], acck[8];
        #pragma unroll
        for (int dd = 0; dd < 8; ++dd) {
            accq[dd] = (double)bq[d0 + dd];
            acck[dd] = (double)bk[d0 + dd];
        }
        for (int fc = 0; fc < 32; ++fc) {
            double dx0 = (double)xs[l * 129 + fc * 4 + 0];
            double dx1 = (double)xs[l * 129 + fc * 4 + 1];
            double dx2 = (double)xs[l * 129 + fc * 4 + 2];
            double dx3 = (double)xs[l * 129 + fc * 4 + 3];
            #pragma unroll
            for (int dd = 0; dd < 8; ++dd) {
                int d = d0 + dd;   // uniform -> scalar loads of weights
                const double* wq = &Wq64[d * NF + fc * 4];
                const double* wk = &Wk64[d * NF + fc * 4];
                accq[dd] += dx0 * wq[0] + dx1 * wq[1] + dx2 * wq[2] + dx3 * wq[3];
                acck[dd] += dx0 * wk[0] + dx1 * wk[1] + dx2 * wk[2] + dx3 * wk[3];
            }
        }
        // f64 [d][n] for repair (coalesced over lane)
        #pragma unroll
        for (int dd = 0; dd < 8; ++dd) {
            size_t idx = ((size_t)b * NDG + d0 + dd) * NN + n0 + l;
            qT64[idx] = accq[dd];
            kT64[idx] = acck[dd];
        }
        // bf16 hi/lo splits, [n][d] layout
        us8v qh0, ql0, kh0, kl0;
        #pragma unroll
        for (int dd = 0; dd < 8; ++dd) {
            float fq = (float)accq[dd];
            unsigned short h1 = bf16_rne(fq);
            unsigned short l1 = bf16_rne(fq - bf16_tof(h1));
            float fk = (float)acck[dd];
            unsigned short h2 = bf16_rne(fk);
            unsigned short l2 = bf16_rne(fk - bf16_tof(h2));
            qh0[dd] = h1; ql0[dd] = l1; kh0[dd] = h2; kl0[dd] = l2;
        }
        size_t nb = ((size_t)b * NN + n0 + l) * NDG + d0;
        *(us8v*)&qh[nb] = qh0;
        *(us8v*)&ql[nb] = ql0;
        *(us8v*)&kh[nb] = kh0;
        *(us8v*)&kl[nb] = kl0;
    }

    // --- h phase (f32, 16 out-features per wave; this block covers f' in [half*64, half*64+64)) ---
    {
        const int fp0 = half * 64 + uw * 16;
        float acc[16];
        #pragma unroll
        for (int i = 0; i < 16; ++i) acc[i] = 0.f;
        for (int fc = 0; fc < 32; ++fc) {
            float x0 = xs[l * 129 + fc * 4 + 0];
            float x1 = xs[l * 129 + fc * 4 + 1];
            float x2 = xs[l * 129 + fc * 4 + 2];
            float x3 = xs[l * 129 + fc * 4 + 3];
            #pragma unroll
            for (int ff = 0; ff < 16; ++ff) {
                const float* wg = &Wg[(fp0 + ff) * NF + fc * 4];
                acc[ff] += x0 * wg[0] + x1 * wg[1] + x2 * wg[2] + x3 * wg[3];
            }
        }
        __syncthreads();   // everyone done reading xs
        #pragma unroll
        for (int ff = 0; ff < 16; ++ff) xs[l * 129 + fp0 + ff] = acc[ff];
        __syncthreads();
        // write h[n][half*64 .. half*64+64) for the 64 nodes
        for (int r = 0; r < 16; ++r) {
            int idx = t + 256 * r;            // 0..4095
            int n = idx >> 6, f = idx & 63;
            h[((size_t)b * NN + n0 + n) * NF + half * 64 + f] = xs[n * 129 + half * 64 + f];
        }
    }
}

#define CE(x,y) { unsigned a_ = v[x], b_ = v[y]; v[x] = a_ > b_ ? a_ : b_; v[y] = a_ > b_ ? b_ : a_; }
__device__ inline void sort16(unsigned v[16]) {
    // Batcher odd-even mergesort 16, descending (63 CE)
    CE(0,1) CE(2,3) CE(4,5) CE(6,7) CE(8,9) CE(10,11) CE(12,13) CE(14,15)
    CE(0,2) CE(1,3) CE(4,6) CE(5,7) CE(8,10) CE(9,11) CE(12,14) CE(13,15)
    CE(1,2) CE(5,6) CE(9,10) CE(13,14)
    CE(0,4) CE(1,5) CE(2,6) CE(3,7) CE(8,12) CE(9,13) CE(10,14) CE(11,15)
    CE(2,4) CE(3,5) CE(10,12) CE(11,13)
    CE(1,2) CE(3,4) CE(5,6) CE(9,10) CE(11,12) CE(13,14)
    CE(0,8) CE(1,9) CE(2,10) CE(3,11) CE(4,12) CE(5,13) CE(6,14) CE(7,15)
    CE(4,8) CE(5,9) CE(6,10) CE(7,11)
    CE(2,4) CE(3,5) CE(6,8) CE(7,9) CE(10,12) CE(11,13)
    CE(1,2) CE(3,4) CE(5,6) CE(7,8) CE(9,10) CE(11,12) CE(13,14)
}
// bitonic clean, 16 elements, descending (32 CE): input bitonic
__device__ inline void clean16(unsigned v[16]) {
    CE(0,8) CE(1,9) CE(2,10) CE(3,11) CE(4,12) CE(5,13) CE(6,14) CE(7,15)
    CE(0,4) CE(1,5) CE(2,6) CE(3,7) CE(8,12) CE(9,13) CE(10,14) CE(11,15)
    CE(0,2) CE(1,3) CE(4,6) CE(5,7) CE(8,10) CE(9,11) CE(12,14) CE(13,15)
    CE(0,1) CE(2,3) CE(4,5) CE(6,7) CE(8,9) CE(10,11) CE(12,13) CE(14,15)
}

// full bitonic sort across 64 lanes, descending (lane 0 = max). 21 substages.
__device__ inline unsigned bsort64(unsigned v, int l) {
    #pragma unroll
    for (int k = 2; k <= 64; k <<= 1) {
        #pragma unroll
        for (int j = k >> 1; j >= 1; j >>= 1) {
            unsigned pv = (unsigned)__shfl_xor((int)v, j, 64);
            bool tm = ((l & k) == 0) == ((l & j) == 0);   // lower lane of desc-run keeps max
            unsigned hi = v > pv ? v : pv;
            unsigned lo = v > pv ? pv : v;
            v = tm ? hi : lo;
        }
    }
    return v;
}

// MFMA bf16-split scores + packed top-15 via threshold prefilter + bitonic sort of survivors.
// grid (64, 32), block 512 (8 waves): wave w computes cols [128w,128w+128); selects rows {2w,2w+1}.
// LDS: single u32 word per score: (code22<<10)|(1023-col), 64 KiB -> 2 blocks/CU.
// Selection: T = 16th-largest of 64 lane-maxima (provably <= true 16th value, E[#>=T] ~ 18);
// compact survivors into this row's (now-dead) LDS region; bitonic-sort64 gives ranks.
// Exact fallback (old sort16 + butterfly merge-tree) when #survivors > 64 (P ~ 1e-26 iid).
__global__ __launch_bounds__(512, 4) void k_score(
    const unsigned short* __restrict__ qh, const unsigned short* __restrict__ ql,
    const unsigned short* __restrict__ kh, const unsigned short* __restrict__ kl,
    int* __restrict__ deg, unsigned int* __restrict__ bmp,
    int* __restrict__ topk, int* __restrict__ wl_cnt, int* __restrict__ wl)
{
    __shared__ unsigned pk[16 * 1024];   // 64 KiB: (code22<<10)|(1023-col), self-describing
    const int t = threadIdx.x, l = t & 63, w = t >> 6;   // w in [0,8)
    const int b = blockIdx.y, row0 = blockIdx.x * 16;
    const int m = l & 15, q4 = l >> 4;

    // A fragments: 16 q rows (hi/lo, two K-halves). A[m][k]: m=lane&15, k=(lane>>4)*8+j
    size_t abase = ((size_t)b * NN + row0 + m) * NDG + q4 * 8;
    s8v ah0 = *(const s8v*)&qh[abase];
    s8v ah1 = *(const s8v*)&qh[abase + 32];
    s8v al0 = *(const s8v*)&ql[abase];
    s8v al1 = *(const s8v*)&ql[abase + 32];

    const int colbase = w * 128;
    #pragma unroll
    for (int tt = 0; tt < 8; ++tt) {
        int col = colbase + tt * 16 + m;
        size_t bbase = ((size_t)b * NN + col) * NDG + q4 * 8;
        s8v bh0 = *(const s8v*)&kh[bbase];
        s8v bh1 = *(const s8v*)&kh[bbase + 32];
        s8v bl0 = *(const s8v*)&kl[bbase];
        s8v bl1 = *(const s8v*)&kl[bbase + 32];
        f4v acc = {0.f, 0.f, 0.f, 0.f};
        acc = __builtin_amdgcn_mfma_f32_16x16x32_bf16(al0, bl0, acc, 0, 0, 0);
        acc = __builtin_amdgcn_mfma_f32_16x16x32_bf16(al1, bl1, acc, 0, 0, 0);
        acc = __builtin_amdgcn_mfma_f32_16x16x32_bf16(ah0, bl0, acc, 0, 0, 0);
        acc = __builtin_amdgcn_mfma_f32_16x16x32_bf16(ah1, bl1, acc, 0, 0, 0);
        acc = __builtin_amdgcn_mfma_f32_16x16x32_bf16(al0, bh0, acc, 0, 0, 0);
        acc = __builtin_amdgcn_mfma_f32_16x16x32_bf16(al1, bh1, acc, 0, 0, 0);
        acc = __builtin_amdgcn_mfma_f32_16x16x32_bf16(ah0, bh0, acc, 0, 0, 0);
        acc = __builtin_amdgcn_mfma_f32_16x16x32_bf16(ah1, bh1, acc, 0, 0, 0);
        // C/D: col=lane&15, row=(lane>>4)*4+reg. XOR-swizzle (q4<<4) keeps stores 2-way (free).
        #pragma unroll
        for (int r = 0; r < 4; ++r) {
            int row  = q4 * 4 + r;           // local 0..15
            int grow = row0 + row;
            float s = acc[r] * 0.125f;
            unsigned c22 = (col == grow) ? 0u : pack22(s);
            pk[row * 1024 + (col ^ (q4 << 4))] = (c22 << 10) | (unsigned)(1023 - col);
        }
    }
    __syncthreads();

    // wave w selects rows 2w, 2w+1
    for (int rr = 0; rr < 2; ++rr) {
        const int row = 2 * w + rr, grow = row0 + row;
        unsigned v[16];
        #pragma unroll
        for (int j = 0; j < 16; ++j)
            v[j] = pk[row * 1024 + l + 64 * j];   // word carries its own col; mapping irrelevant

        // per-lane max
        unsigned lmax = v[0];
        #pragma unroll
        for (int j = 1; j < 16; ++j) lmax = v[j] > lmax ? v[j] : lmax;

        // T = 16th-largest lane max (valid lower bound for the global 16th value)
        unsigned sm = bsort64(lmax, l);
        unsigned T = (unsigned)__shfl((int)sm, 15, 64);

        // count + exclusive prefix of survivors
        int cnt = 0;
        #pragma unroll
        for (int j = 0; j < 16; ++j) cnt += (v[j] >= T) ? 1 : 0;
        int pre = cnt;
        #pragma unroll
        for (int d = 1; d < 64; d <<= 1) {
            int o = __shfl_up(pre, d, 64);
            if (l >= d) pre += o;
        }
        const int C = __shfl(pre, 63, 64);
        int off = pre - cnt;

        unsigned res;   // lane l ends holding the rank-l value (l < 16 meaningful)
        if (C <= 64) {
            // compact survivors into this row's LDS region (its data is now in regs)
            unsigned* scr = &pk[row * 1024];
            #pragma unroll
            for (int j = 0; j < 16; ++j)
                if (v[j] >= T) scr[off++] = v[j];
            unsigned cv = (l < C) ? scr[l] : 0u;   // in-wave DS ordering: safe
            res = bsort64(cv, l);
        } else {
            // exact fallback: old sort16 + butterfly merge-tree (adversarial data only)
            sort16(v);
            #pragma unroll
            for (int offb = 1; offb < 64; offb <<= 1) {
                unsigned pv[16];
                #pragma unroll
                for (int i = 0; i < 16; ++i) pv[i] = (unsigned)__shfl_xor((int)v[i], offb, 64);
                #pragma unroll
                for (int i = 0; i < 8; ++i) {
                    unsigned a0 = v[i], b0 = pv[15 - i];
                    unsigned a1 = v[15 - i], b1 = pv[i];
                    v[i]      = a0 > b0 ? a0 : b0;
                    v[15 - i] = a1 > b1 ? a1 : b1;
                }
                clean16(v);
            }
            unsigned rsel = v[15];
            #pragma unroll
            for (int j = 0; j < 15; ++j) if (l == j) rsel = v[j];
            res = rsel;
        }

        // ranks 14 (15th) and 15 (16th) drive the precision flag
        unsigned r14 = (unsigned)__shfl((int)res, 14, 64);
        unsigned r15 = (unsigned)__shfl((int)res, 15, 64);
        float s15 = dec22(r14 >> 10), s16 = dec22(r15 >> 10);
        unsigned e15 = (__float_as_uint(fabsf(s15)) >> 23) & 255u;
        unsigned e16 = (__float_as_uint(fabsf(s16)) >> 23) & 255u;
        unsigned e = e15 > e16 ? e15 : e16;
        float qq = __uint_as_float((e - 17) << 23);    // 22-bit code quantum at this magnitude
        bool flagged = (s15 - s16) < (4.f * qq + 1e-4f);
        if (l < 15) {
            int col = 1023 - (int)(res & 1023u);
            atomicAdd(&deg[b * NN + col], 1);
            atomicOr(&bmp[((size_t)b * NN + col) * 32 + (grow >> 5)], 1u << (grow & 31));
            if (flagged) topk[(b * NN + grow) * 16 + l] = col;
        }
        if (l == 0 && flagged) {
            int idx = atomicAdd(wl_cnt, 1);
            if (idx < 32767) wl[idx] = b * NN + grow;
        }
    }
}

// exact f64 re-selection for worklist rows; patches deg/bitmap by set-diff.
// grid 1024, block 64: ~one block per flagged row, fully concurrent; d-loop double-buffered.
__global__ __launch_bounds__(64) void k_repair(
    const double* __restrict__ qT64, const double* __restrict__ kT64,
    const int* __restrict__ topk, const int* __restrict__ wl_cnt, const int* __restrict__ wl,
    int* __restrict__ deg, unsigned int* __restrict__ bmp)
{
    const int l = threadIdx.x;
    __shared__ double qld[64];
    __shared__ int oldset[15], newset[15];
    const double NEGINF = -__builtin_inf();
    int n = wl_cnt[0]; if (n > 32767) n = 32767;

    for (int i = blockIdx.x; i < n; i += 1024) {
        int rg = wl[i];
        int b = rg >> 10, row = rg & 1023;

        __syncthreads();
        qld[l] = qT64[((size_t)b * NDG + l) * NN + row];
        if (l < 15) oldset[l] = topk[(b * NN + row) * 16 + l];
        __syncthreads();

        double sc[16];
        #pragma unroll
        for (int tt = 0; tt < 16; ++tt) sc[tt] = 0.0;
        const double* kb = &kT64[(size_t)b * NDG * NN];
        double buf[16];
        #pragma unroll
        for (int tt = 0; tt < 16; ++tt) buf[tt] = kb[l + 64 * tt];
        for (int d = 0; d < 64; ++d) {
            double nb[16];
            if (d < 63) {
                const double* kr = kb + (size_t)(d + 1) * NN;
                #pragma unroll
                for (int tt = 0; tt < 16; ++tt) nb[tt] = kr[l + 64 * tt];
            }
            double qd = qld[d];
            #pragma unroll
            for (int tt = 0; tt < 16; ++tt) sc[tt] += qd * buf[tt];
            if (d < 63) {
                #pragma unroll
                for (int tt = 0; tt < 16; ++tt) buf[tt] = nb[tt];
            }
        }
        #pragma unroll
        for (int tt = 0; tt < 16; ++tt) if (l + 64 * tt == row) sc[tt] = NEGINF;

        for (int it = 0; it < 15; ++it) {
            double lv = NEGINF; int lc = 0x7fffffff;
            #pragma unroll
            for (int tt = 0; tt < 16; ++tt)
                if (sc[tt] > lv) { lv = sc[tt]; lc = l + 64 * tt; }
            #pragma unroll
            for (int off = 1; off < 64; off <<= 1) {
                double ov = __shfl_xor(lv, off, 64);
                int    oc = __shfl_xor(lc, off, 64);
                if (ov > lv || (ov == lv && oc < lc)) { lv = ov; lc = oc; }
            }
            #pragma unroll
            for (int tt = 0; tt < 16; ++tt) if (l + 64 * tt == lc) sc[tt] = NEGINF;
            if (l == 0) newset[it] = lc;
        }
        __syncthreads();
        if (l < 15) {
            int cn = newset[l];
            bool found = false;
            #pragma unroll
            for (int j = 0; j < 15; ++j) found = found || (oldset[j] == cn);
            if (!found) {
                atomicAdd(&deg[b * NN + cn], 1);
                atomicOr(&bmp[((size_t)b * NN + cn) * 32 + (row >> 5)], 1u << (row & 31));
            }
            int co = oldset[l];
            found = false;
            #pragma unroll
            for (int j = 0; j < 15; ++j) found = found || (newset[j] == co);
            if (!found) {
                atomicSub(&deg[b * NN + co], 1);
                atomicAnd(&bmp[((size_t)b * NN + co) * 32 + (row >> 5)], ~(1u << (row & 31)));
            }
        }
    }
}

// gather per target via compacted LDS edge list + LDS norm table (dinv folded here).
// grid (1024,32), block 128 (f = thread).
__global__ __launch_bounds__(128) void k_gather(
    const float* __restrict__ h, const float* __restrict__ bg,
    const int* __restrict__ deg, const unsigned int* __restrict__ bmp,
    float* __restrict__ tmp)
{
    __shared__ int list[1024];
    __shared__ float nrm[1024];
    __shared__ int scnt;
    const int tgt = blockIdx.x, b = blockIdx.y, t = threadIdx.x;
    if (t < 32) {
        unsigned word = bmp[((size_t)b * NN + tgt) * 32 + t];
        int pc = __popc(word);
        int pre = pc;
        #pragma unroll
        for (int d = 1; d < 32; d <<= 1) {
            int o = __shfl_up(pre, d, 32);
            if (t >= d) pre += o;
        }
        if (t == 31) scnt = pre;
        int idx = pre - pc;
        while (word) {
            int s = __ffs(word) - 1;
            word &= word - 1;
            list[idx++] = t * 32 + s;
        }
    }
    __syncthreads();
    const int cnt = scnt;
    for (int e = t; e < cnt; e += 128)
        nrm[e] = rsqrtf((float)(deg[b * NN + list[e]] + 2));
    __syncthreads();
    const int f = t;
    float dt = rsqrtf((float)(deg[b * NN + tgt] + 2));
    float acc = 2.0f * dt * h[((size_t)b * NN + tgt) * NF + f];
    for (int e = 0; e < cnt; ++e) {
        int src = list[e];
        acc += h[((size_t)b * NN + src) * NF + f] * nrm[e];
    }
    tmp[((size_t)b * NN + tgt) * NF + f] = bg[f] + dt * acc;
}

// [b][n][f] -> [b][f][n]. grid (32, 4, 32), block 256.
__global__ __launch_bounds__(256) void k_transpose(const float* __restrict__ tmp,
                                                   float* __restrict__ out)
{
    __shared__ float tile[32][33];
    const int t = threadIdx.x;
    const int n0 = blockIdx.x * 32, f0 = blockIdx.y * 32, b = blockIdx.z;
    const int c = t & 31, rb = t >> 5;
    #pragma unroll
    for (int i = 0; i < 4; ++i) {
        int r = rb + i * 8;
        tile[r][c] = tmp[((size_t)b * NN + n0 + r) * NF + f0 + c];
    }
    __syncthreads();
    #pragma unroll
    for (int i = 0; i < 4; ++i) {
        int r = rb + i * 8;
        out[((size_t)b * NF + f0 + r) * NN + n0 + c] = tile[c][r];
    }
}

extern "C" void kernel_launch(void* const* d_in, const int* in_sizes, int n_in,
                              void* d_out, int out_size, void* d_ws, size_t ws_size,
                              hipStream_t stream)
{
    const float* x  = (const float*)d_in[0];
    const float* Wq = (const float*)d_in[1];
    const float* bq = (const float*)d_in[2];
    const float* Wk = (const float*)d_in[3];
    const float* bk = (const float*)d_in[4];
    const float* Wg = (const float*)d_in[5];
    const float* bg = (const float*)d_in[6];
    float* out = (float*)d_out;
    char* ws = (char*)d_ws;

    unsigned short* qh = (unsigned short*)(ws + OFF_QH);
    unsigned short* ql = (unsigned short*)(ws + OFF_QL);
    unsigned short* kh = (unsigned short*)(ws + OFF_KH);
    unsigned short* kl = (unsigned short*)(ws + OFF_KL);
    float*          h   = (float*)(ws + OFF_H);
    int*            deg = (int*)(ws + OFF_DEG);
    unsigned int*   bmp = (unsigned int*)(ws + OFF_BMP);
    int*            wlc = (int*)(ws + OFF_WL);
    int*            wl  = wlc + 1;
    int*            tpk = (int*)(ws + OFF_TOPK);
    double*         Wq64 = (double*)(ws + OFF_W64);
    double*         Wk64 = Wq64 + 8192;
    double*         qT64 = (double*)(ws + OFF_QT64);
    double*         kT64 = (double*)(ws + OFF_KT64);
    float*          tmp  = (float*)(ws + OFF_TMP);

    k_upcast<<<32, 256, 0, stream>>>(Wq, Wk, Wq64, Wk64);
    // zero range: deg + bmp + wl_cnt = 4,325,392 B = 270337 uint4 (done inside k_prep)
    k_prep<<<dim3(16, 2, 32), 256, 0, stream>>>(x, bq, bk, Wq64, Wk64, Wg,
                                                qh, ql, kh, kl, qT64, kT64, h,
                                                (uint4*)(ws + OFF_DEG), 270337);
    k_score<<<dim3(64, 32), 512, 0, stream>>>(qh, ql, kh, kl, deg, bmp, tpk, wlc, wl);
    k_repair<<<1024, 64, 0, stream>>>(qT64, kT64, tpk, wlc, wl, deg, bmp);
    k_gather<<<dim3(1024, 32), 128, 0, stream>>>(h, bg, deg, bmp, tmp);
    k_transpose<<<dim3(32, 4, 32), 256, 0, stream>>>(tmp, out);
}

// Round 2
// 311.202 us; speedup vs baseline: 1.0186x; 1.0186x over previous
//
#include <hip/hip_runtime.h>

#define NBATCH 32
#define NN     1024     // d_model = number of nodes
#define NF     128      // win_size = node feature dim
#define NDG    64       // graph embed dim
#define TOPK   15

// ---------------- workspace layout (bytes) ----------------
#define OFF_QH    ((size_t)0)            // bf16-hi q [32][1024][64]  4 MiB
#define OFF_QL    ((size_t)4194304)      // bf16-lo q                 4 MiB
#define OFF_KH    ((size_t)8388608)      // bf16-hi k                 4 MiB
#define OFF_KL    ((size_t)12582912)     // bf16-lo k                 4 MiB
#define OFF_H     ((size_t)16777216)     // f32 [32][1024][128]      16 MiB
#define OFF_DEG   ((size_t)33554432)     // i32 [32][1024]          128 KiB
#define OFF_BMP   ((size_t)33685504)     // u32 [32][1024][32]        4 MiB
#define OFF_WL    ((size_t)37879808)     // wl_cnt + wl[32767]      128 KiB
#define OFF_TOPK  ((size_t)38010880)     // i32 [32][1024][16]        2 MiB
#define OFF_W64   ((size_t)40108032)     // f64 Wq64[8192], Wk64[8192] 128 KiB
#define OFF_QT64  ((size_t)40239104)     // f64 [32][64][1024]       16 MiB
#define OFF_KT64  ((size_t)57016320)     // f64 [32][64][1024]       16 MiB
#define OFF_TMP   ((size_t)0)            // f32 [32][1024][128]      16 MiB (overlaps QH..KL, dead by then)

typedef short s8v  __attribute__((ext_vector_type(8)));   // 8 bf16 (4 VGPRs) MFMA operand
typedef float f4v  __attribute__((ext_vector_type(4)));   // MFMA accumulator
typedef unsigned short us8v __attribute__((ext_vector_type(8)));

__device__ inline unsigned short bf16_rne(float f) {
    unsigned u = __float_as_uint(f);
    return (unsigned short)((u + 0x7FFFu + ((u >> 16) & 1u)) >> 16);
}
__device__ inline float bf16_tof(unsigned short h) { return __uint_as_float(((unsigned)h) << 16); }

// monotone 22-bit code for f32 score in window [-4, 4): sign + 5-bit biased exp + 16-bit mantissa
__device__ inline unsigned pack22(float s) {
    unsigned u   = __float_as_uint(s);
    int      mag = (int)(u & 0x7FFFFFFFu);
    int      t   = mag - 0x38800000;                 // bias at 2^-14
    t = t < 0 ? 0 : (t > 0x07FFFFFF ? 0x07FFFFFF : t);
    unsigned ts = (unsigned)t >> 6;                  // 21 bits
    return ((int)u < 0) ? (0x1FFFFFu - ts) : (0x200000u | ts);
}
__device__ inline float dec22(unsigned val22) {
    bool pos = (val22 & 0x200000u) != 0;
    unsigned ts = pos ? (val22 & 0x1FFFFFu) : (0x1FFFFFu - (val22 & 0x1FFFFFu));
    float f = __uint_as_float((ts << 6) + 0x38800000u);
    return pos ? f : -f;
}

__global__ __launch_bounds__(256) void k_upcast(const float* __restrict__ Wq,
                                                const float* __restrict__ Wk,
                                                double* __restrict__ Wq64,
                                                double* __restrict__ Wk64) {
    int i = blockIdx.x * 256 + threadIdx.x;  // 0..8191
    Wq64[i] = (double)Wq[i];
    Wk64[i] = (double)Wk[i];
}

// Fused: zero deg/bmp/wl_cnt + q,k f64 (repair path) + bf16 hi/lo splits + h = nf@Wg.T.
// grid (16 node-tiles, 2 halves, 32 batch), block 256. lane = node within 64-node tile.
__global__ __launch_bounds__(256) void k_prep(
    const float* __restrict__ x, const float* __restrict__ bq, const float* __restrict__ bk,
    const double* __restrict__ Wq64, const double* __restrict__ Wk64,
    const float* __restrict__ Wg,
    unsigned short* __restrict__ qh, unsigned short* __restrict__ ql,
    unsigned short* __restrict__ kh, unsigned short* __restrict__ kl,
    double* __restrict__ qT64, double* __restrict__ kT64,
    float* __restrict__ h,
    uint4* __restrict__ zbase, int zn)
{
    __shared__ float xs[64 * 129];   // xs[node][f], pad 129 -> conflict-free
    const int t = threadIdx.x;
    const int l = t & 63;
    const int w = t >> 6;
    const int uw = __builtin_amdgcn_readfirstlane(w);
    const int n0 = blockIdx.x * 64;
    const int half = blockIdx.y;
    const int b  = blockIdx.z;

    // --- zero phase (deg + bmp + wl_cnt), grid-stride over 1024 blocks ---
    {
        int lid = ((b * 2 + half) * 16 + blockIdx.x) * 256 + t;   // 0..262143
        for (int i = lid; i < zn; i += 262144)
            zbase[i] = make_uint4(0u, 0u, 0u, 0u);
    }

    {   // xs[node][f] = x[b][f][n0+node]  (coalesced over node)
        const int j = t & 63, fg = t >> 6;
        for (int ff = 0; ff < 32; ++ff) {
            int f = fg + ff * 4;
            xs[j * 129 + f] = x[((size_t)b * NF + f) * NN + n0 + j];
        }
    }
    __syncthreads();

    // --- q/k phase (f64, 8 d-dims per wave) ---
    {
        const int d0 = half * 32 + uw * 8;
        double accq[8], acck[8];
        #pragma unroll
        for (int dd = 0; dd < 8; ++dd) {
            accq[dd] = (double)bq[d0 + dd];
            acck[dd] = (double)bk[d0 + dd];
        }
        for (int fc = 0; fc < 32; ++fc) {
            double dx0 = (double)xs[l * 129 + fc * 4 + 0];
            double dx1 = (double)xs[l * 129 + fc * 4 + 1];
            double dx2 = (double)xs[l * 129 + fc * 4 + 2];
            double dx3 = (double)xs[l * 129 + fc * 4 + 3];
            #pragma unroll
            for (int dd = 0; dd < 8; ++dd) {
                int d = d0 + dd;   // uniform -> scalar loads of weights
                const double* wq = &Wq64[d * NF + fc * 4];
                const double* wk = &Wk64[d * NF + fc * 4];
                accq[dd] += dx0 * wq[0] + dx1 * wq[1] + dx2 * wq[2] + dx3 * wq[3];
                acck[dd] += dx0 * wk[0] + dx1 * wk[1] + dx2 * wk[2] + dx3 * wk[3];
            }
        }
        // f64 [d][n] for repair (coalesced over lane)
        #pragma unroll
        for (int dd = 0; dd < 8; ++dd) {
            size_t idx = ((size_t)b * NDG + d0 + dd) * NN + n0 + l;
            qT64[idx] = accq[dd];
            kT64[idx] = acck[dd];
        }
        // bf16 hi/lo splits, [n][d] layout
        us8v qh0, ql0, kh0, kl0;
        #pragma unroll
        for (int dd = 0; dd < 8; ++dd) {
            float fq = (float)accq[dd];
            unsigned short h1 = bf16_rne(fq);
            unsigned short l1 = bf16_rne(fq - bf16_tof(h1));
            float fk = (float)acck[dd];
            unsigned short h2 = bf16_rne(fk);
            unsigned short l2 = bf16_rne(fk - bf16_tof(h2));
            qh0[dd] = h1; ql0[dd] = l1; kh0[dd] = h2; kl0[dd] = l2;
        }
        size_t nb = ((size_t)b * NN + n0 + l) * NDG + d0;
        *(us8v*)&qh[nb] = qh0;
        *(us8v*)&ql[nb] = ql0;
        *(us8v*)&kh[nb] = kh0;
        *(us8v*)&kl[nb] = kl0;
    }

    // --- h phase (f32, 16 out-features per wave; this block covers f' in [half*64, half*64+64)) ---
    {
        const int fp0 = half * 64 + uw * 16;
        float acc[16];
        #pragma unroll
        for (int i = 0; i < 16; ++i) acc[i] = 0.f;
        for (int fc = 0; fc < 32; ++fc) {
            float x0 = xs[l * 129 + fc * 4 + 0];
            float x1 = xs[l * 129 + fc * 4 + 1];
            float x2 = xs[l * 129 + fc * 4 + 2];
            float x3 = xs[l * 129 + fc * 4 + 3];
            #pragma unroll
            for (int ff = 0; ff < 16; ++ff) {
                const float* wg = &Wg[(fp0 + ff) * NF + fc * 4];
                acc[ff] += x0 * wg[0] + x1 * wg[1] + x2 * wg[2] + x3 * wg[3];
            }
        }
        __syncthreads();   // everyone done reading xs
        #pragma unroll
        for (int ff = 0; ff < 16; ++ff) xs[l * 129 + fp0 + ff] = acc[ff];
        __syncthreads();
        // write h[n][half*64 .. half*64+64) for the 64 nodes
        for (int r = 0; r < 16; ++r) {
            int idx = t + 256 * r;            // 0..4095
            int n = idx >> 6, f = idx & 63;
            h[((size_t)b * NN + n0 + n) * NF + half * 64 + f] = xs[n * 129 + half * 64 + f];
        }
    }
}

// full bitonic sort across 64 lanes, descending (lane 0 = max). 21 substages.
__device__ inline unsigned bsort64(unsigned v, int l) {
    #pragma unroll
    for (int k = 2; k <= 64; k <<= 1) {
        #pragma unroll
        for (int j = k >> 1; j >= 1; j >>= 1) {
            unsigned pv = (unsigned)__shfl_xor((int)v, j, 64);
            bool tm = ((l & k) == 0) == ((l & j) == 0);   // lower lane of desc-run keeps max
            unsigned hi = v > pv ? v : pv;
            unsigned lo = v > pv ? pv : v;
            v = tm ? hi : lo;
        }
    }
    return v;
}

// two independent bitonic sort64 chains interleaved (latency overlap)
__device__ inline void bsort64_2(unsigned& va, unsigned& vb, int l) {
    #pragma unroll
    for (int k = 2; k <= 64; k <<= 1) {
        #pragma unroll
        for (int j = k >> 1; j >= 1; j >>= 1) {
            unsigned pa = (unsigned)__shfl_xor((int)va, j, 64);
            unsigned pb = (unsigned)__shfl_xor((int)vb, j, 64);
            bool tm = ((l & k) == 0) == ((l & j) == 0);
            unsigned ha = va > pa ? va : pa, la = va > pa ? pa : va;
            unsigned hb = vb > pb ? vb : pb, lb = vb > pb ? pb : vb;
            va = tm ? ha : la;
            vb = tm ? hb : lb;
        }
    }
}

// MFMA bf16-split scores + statistical-threshold prefilter at the SOURCE.
// grid (64, 32), block 512 (8 waves): wave w computes cols [128w,128w+128); merges rows {2w,2w+1}.
// Per-row threshold t_r = mean_r + 1.7*std_r computed from q-row stats (scores ~ N(q.bk/8, |q|^2/64));
// survivors (E~46/row of 1024) ballot-compacted into slots[row][wave][32] (16.4 KiB LDS total).
// Merge: read 256 slots (1 ds_read_b128/lane), 16th-lane-max threshold, compact, bsort64 -> ranks.
// Exactness guard: <16 survivors / slot overflow / >64 post-filter -> dummy set + flagged=true,
// and the existing exact-f64 k_repair replaces it (same contract as near-tie rows).
__global__ __launch_bounds__(512, 6) void k_score(
    const unsigned short* __restrict__ qh, const unsigned short* __restrict__ ql,
    const unsigned short* __restrict__ kh, const unsigned short* __restrict__ kl,
    const float* __restrict__ bk,
    int* __restrict__ deg, unsigned int* __restrict__ bmp,
    int* __restrict__ topk, int* __restrict__ wl_cnt, int* __restrict__ wl)
{
    __shared__ __align__(16) unsigned slots[16 * 256];   // [row][wave][32] u32, 16 KiB
    __shared__ unsigned rowflag[16];                     // per-row overflow flag
    const int t = threadIdx.x, l = t & 63, w = t >> 6;   // w in [0,8)
    const int b = blockIdx.y, row0 = blockIdx.x * 16;
    const int m = l & 15, q4 = l >> 4;

    // zero slots + flags
    {
        uint4* z = (uint4*)slots;
        z[t]       = make_uint4(0u, 0u, 0u, 0u);
        z[t + 512] = make_uint4(0u, 0u, 0u, 0u);
        if (t < 16) rowflag[t] = 0u;
    }

    // A fragments: 16 q rows (hi/lo, two K-halves). A[m][k]: m=lane&15, k=(lane>>4)*8+j
    size_t abase = ((size_t)b * NN + row0 + m) * NDG + q4 * 8;
    s8v ah0 = *(const s8v*)&qh[abase];
    s8v ah1 = *(const s8v*)&qh[abase + 32];
    s8v al0 = *(const s8v*)&ql[abase];
    s8v al1 = *(const s8v*)&ql[abase + 32];

    // per-row score stats from q fragments: lane holds row m, dims {q4*8..+8} u {q4*8+32..+8}
    unsigned Trow[4];
    {
        float ssq = 0.f, smn = 0.f;
        #pragma unroll
        for (int j = 0; j < 8; ++j) {
            float q0 = bf16_tof(((us8v)ah0)[j]) + bf16_tof(((us8v)al0)[j]);
            float q1 = bf16_tof(((us8v)ah1)[j]) + bf16_tof(((us8v)al1)[j]);
            float b0 = bk[q4 * 8 + j];
            float b1 = bk[q4 * 8 + 32 + j];
            ssq += q0 * q0 + q1 * q1;
            smn += q0 * b0 + q1 * b1;
        }
        ssq += __shfl_xor(ssq, 16, 64); ssq += __shfl_xor(ssq, 32, 64);
        smn += __shfl_xor(smn, 16, 64); smn += __shfl_xor(smn, 32, 64);
        // t_m: threshold for row m. scores ~ N(smn/8, ssq/64): t = mean + 1.7*std
        float t_m = 0.125f * smn + 0.2125f * __builtin_sqrtf(ssq);   // 1.7/8 = 0.2125
        unsigned Tm = pack22(t_m) << 10;
        // redistribute: this lane's acc rows are 4*q4+r; their T lives at lane (4*q4+r)
        #pragma unroll
        for (int r = 0; r < 4; ++r)
            Trow[r] = (unsigned)__shfl((int)Tm, 4 * q4 + r, 64);
    }
    __syncthreads();   // slot-zeroing visible before survivor writes

    const int colbase = w * 128;
    unsigned basec[4] = {0u, 0u, 0u, 0u};
    #pragma unroll
    for (int tt = 0; tt < 8; ++tt) {
        int col = colbase + tt * 16 + m;
        size_t bbase = ((size_t)b * NN + col) * NDG + q4 * 8;
        s8v bh0 = *(const s8v*)&kh[bbase];
        s8v bh1 = *(const s8v*)&kh[bbase + 32];
        s8v bl0 = *(const s8v*)&kl[bbase];
        s8v bl1 = *(const s8v*)&kl[bbase + 32];
        f4v acc = {0.f, 0.f, 0.f, 0.f};
        acc = __builtin_amdgcn_mfma_f32_16x16x32_bf16(al0, bl0, acc, 0, 0, 0);
        acc = __builtin_amdgcn_mfma_f32_16x16x32_bf16(al1, bl1, acc, 0, 0, 0);
        acc = __builtin_amdgcn_mfma_f32_16x16x32_bf16(ah0, bl0, acc, 0, 0, 0);
        acc = __builtin_amdgcn_mfma_f32_16x16x32_bf16(ah1, bl1, acc, 0, 0, 0);
        acc = __builtin_amdgcn_mfma_f32_16x16x32_bf16(al0, bh0, acc, 0, 0, 0);
        acc = __builtin_amdgcn_mfma_f32_16x16x32_bf16(al1, bh1, acc, 0, 0, 0);
        acc = __builtin_amdgcn_mfma_f32_16x16x32_bf16(ah0, bh0, acc, 0, 0, 0);
        acc = __builtin_amdgcn_mfma_f32_16x16x32_bf16(ah1, bh1, acc, 0, 0, 0);
        // C/D: col=lane&15, row=(lane>>4)*4+reg. Ballot-compact survivors per (row, wave).
        #pragma unroll
        for (int r = 0; r < 4; ++r) {
            int row  = q4 * 4 + r;           // local 0..15
            int grow = row0 + row;
            float s = acc[r] * 0.125f;
            unsigned c22 = (col == grow) ? 0u : pack22(s);
            unsigned v = (c22 << 10) | (unsigned)(1023 - col);
            bool p = v >= Trow[r];
            unsigned long long mk = __ballot(p);
            unsigned w16 = (unsigned)(mk >> (q4 * 16)) & 0xFFFFu;
            unsigned idx = basec[r] + (unsigned)__popc(w16 & ((1u << m) - 1u));
            if (p && idx < 32u) slots[row * 256 + w * 32 + (int)idx] = v;
            basec[r] += (unsigned)__popc(w16);
        }
    }
    #pragma unroll
    for (int r = 0; r < 4; ++r)
        if (m == 0 && basec[r] > 32u) rowflag[q4 * 4 + r] = 1u;   // benign same-value race
    __syncthreads();

    // wave w merges rows 2w, 2w+1 (interleaved chains)
    const int rA = 2 * w, rB = 2 * w + 1;
    uint4 ca = *(const uint4*)&slots[rA * 256 + l * 4];
    uint4 cb = *(const uint4*)&slots[rB * 256 + l * 4];

    unsigned mxa = ca.x > ca.y ? ca.x : ca.y;  mxa = mxa > ca.z ? mxa : ca.z;  mxa = mxa > ca.w ? mxa : ca.w;
    unsigned mxb = cb.x > cb.y ? cb.x : cb.y;  mxb = mxb > cb.z ? mxb : cb.z;  mxb = mxb > cb.w ? mxb : cb.w;
    bsort64_2(mxa, mxb, l);
    unsigned Ta = (unsigned)__shfl((int)mxa, 15, 64);
    unsigned Tb = (unsigned)__shfl((int)mxb, 15, 64);

    // survivors: v >= T && v != 0 (if T==0, <16 nonzero lane-maxima => total nonzero < 64: safe)
    int ka0 = (ca.x >= Ta && ca.x) ? 1 : 0, ka1 = (ca.y >= Ta && ca.y) ? 1 : 0;
    int ka2 = (ca.z >= Ta && ca.z) ? 1 : 0, ka3 = (ca.w >= Ta && ca.w) ? 1 : 0;
    int kb0 = (cb.x >= Tb && cb.x) ? 1 : 0, kb1 = (cb.y >= Tb && cb.y) ? 1 : 0;
    int kb2 = (cb.z >= Tb && cb.z) ? 1 : 0, kb3 = (cb.w >= Tb && cb.w) ? 1 : 0;
    int cntA = ka0 + ka1 + ka2 + ka3;
    int cntB = kb0 + kb1 + kb2 + kb3;
    int preA = cntA, preB = cntB;
    #pragma unroll
    for (int d = 1; d < 64; d <<= 1) {
        int oA = __shfl_up(preA, d, 64);
        int oB = __shfl_up(preB, d, 64);
        if (l >= d) { preA += oA; preB += oB; }
    }
    const int CA = __shfl(preA, 63, 64);
    const int CB = __shfl(preB, 63, 64);

    {   // compact row A survivors into its own (now-consumed) region
        unsigned* scr = &slots[rA * 256];
        int off = preA - cntA;
        if (ka0) scr[off++] = ca.x;
        if (ka1) scr[off++] = ca.y;
        if (ka2) scr[off++] = ca.z;
        if (ka3) scr[off++] = ca.w;
    }
    {   // compact row B
        unsigned* scr = &slots[rB * 256];
        int off = preB - cntB;
        if (kb0) scr[off++] = cb.x;
        if (kb1) scr[off++] = cb.y;
        if (kb2) scr[off++] = cb.z;
        if (kb3) scr[off++] = cb.w;
    }
    unsigned cva = (l < CA && l < 64) ? slots[rA * 256 + l] : 0u;
    unsigned cvb = (l < CB && l < 64) ? slots[rB * 256 + l] : 0u;
    bsort64_2(cva, cvb, l);   // lane l = rank-l value (descending)

    // emit both rows
    #pragma unroll
    for (int rr = 0; rr < 2; ++rr) {
        const int row  = rr == 0 ? rA : rB;
        const int grow = row0 + row;
        unsigned res   = rr == 0 ? cva : cvb;
        const int C2   = rr == 0 ? CA : CB;

        unsigned r14 = (unsigned)__shfl((int)res, 14, 64);
        unsigned r15 = (unsigned)__shfl((int)res, 15, 64);
        bool fb = (rowflag[row] != 0u) || (C2 > 64) || (r15 == 0u);

        bool flagged;
        if (fb) {
            flagged = true;
        } else {
            float s15 = dec22(r14 >> 10), s16 = dec22(r15 >> 10);
            unsigned e15 = (__float_as_uint(fabsf(s15)) >> 23) & 255u;
            unsigned e16 = (__float_as_uint(fabsf(s16)) >> 23) & 255u;
            unsigned e = e15 > e16 ? e15 : e16;
            float qq = __uint_as_float((e - 17) << 23);    // 22-bit code quantum at this magnitude
            flagged = (s15 - s16) < (4.f * qq + 1e-4f);
        }
        if (l < 15) {
            int col = fb ? ((grow + 1 + l) & 1023)          // dummy distinct non-self set
                         : (1023 - (int)(res & 1023u));
            atomicAdd(&deg[b * NN + col], 1);
            atomicOr(&bmp[((size_t)b * NN + col) * 32 + (grow >> 5)], 1u << (grow & 31));
            if (flagged) topk[(b * NN + grow) * 16 + l] = col;
        }
        if (l == 0 && flagged) {
            int idx = atomicAdd(wl_cnt, 1);
            if (idx < 32767) wl[idx] = b * NN + grow;
        }
    }
}

// exact f64 re-selection for worklist rows; patches deg/bitmap by set-diff.
// grid 1024, block 64: ~one block per flagged row, fully concurrent; d-loop double-buffered.
__global__ __launch_bounds__(64) void k_repair(
    const double* __restrict__ qT64, const double* __restrict__ kT64,
    const int* __restrict__ topk, const int* __restrict__ wl_cnt, const int* __restrict__ wl,
    int* __restrict__ deg, unsigned int* __restrict__ bmp)
{
    const int l = threadIdx.x;
    __shared__ double qld[64];
    __shared__ int oldset[15], newset[15];
    const double NEGINF = -__builtin_inf();
    int n = wl_cnt[0]; if (n > 32767) n = 32767;

    for (int i = blockIdx.x; i < n; i += 1024) {
        int rg = wl[i];
        int b = rg >> 10, row = rg & 1023;

        __syncthreads();
        qld[l] = qT64[((size_t)b * NDG + l) * NN + row];
        if (l < 15) oldset[l] = topk[(b * NN + row) * 16 + l];
        __syncthreads();

        double sc[16];
        #pragma unroll
        for (int tt = 0; tt < 16; ++tt) sc[tt] = 0.0;
        const double* kb = &kT64[(size_t)b * NDG * NN];
        double buf[16];
        #pragma unroll
        for (int tt = 0; tt < 16; ++tt) buf[tt] = kb[l + 64 * tt];
        for (int d = 0; d < 64; ++d) {
            double nb[16];
            if (d < 63) {
                const double* kr = kb + (size_t)(d + 1) * NN;
                #pragma unroll
                for (int tt = 0; tt < 16; ++tt) nb[tt] = kr[l + 64 * tt];
            }
            double qd = qld[d];
            #pragma unroll
            for (int tt = 0; tt < 16; ++tt) sc[tt] += qd * buf[tt];
            if (d < 63) {
                #pragma unroll
                for (int tt = 0; tt < 16; ++tt) buf[tt] = nb[tt];
            }
        }
        #pragma unroll
        for (int tt = 0; tt < 16; ++tt) if (l + 64 * tt == row) sc[tt] = NEGINF;

        for (int it = 0; it < 15; ++it) {
            double lv = NEGINF; int lc = 0x7fffffff;
            #pragma unroll
            for (int tt = 0; tt < 16; ++tt)
                if (sc[tt] > lv) { lv = sc[tt]; lc = l + 64 * tt; }
            #pragma unroll
            for (int off = 1; off < 64; off <<= 1) {
                double ov = __shfl_xor(lv, off, 64);
                int    oc = __shfl_xor(lc, off, 64);
                if (ov > lv || (ov == lv && oc < lc)) { lv = ov; lc = oc; }
            }
            #pragma unroll
            for (int tt = 0; tt < 16; ++tt) if (l + 64 * tt == lc) sc[tt] = NEGINF;
            if (l == 0) newset[it] = lc;
        }
        __syncthreads();
        if (l < 15) {
            int cn = newset[l];
            bool found = false;
            #pragma unroll
            for (int j = 0; j < 15; ++j) found = found || (oldset[j] == cn);
            if (!found) {
                atomicAdd(&deg[b * NN + cn], 1);
                atomicOr(&bmp[((size_t)b * NN + cn) * 32 + (row >> 5)], 1u << (row & 31));
            }
            int co = oldset[l];
            found = false;
            #pragma unroll
            for (int j = 0; j < 15; ++j) found = found || (newset[j] == co);
            if (!found) {
                atomicSub(&deg[b * NN + co], 1);
                atomicAnd(&bmp[((size_t)b * NN + co) * 32 + (row >> 5)], ~(1u << (row & 31)));
            }
        }
    }
}

// gather per target via compacted LDS edge list + LDS norm table (dinv folded here).
// grid (1024,32), block 128 (f = thread).
__global__ __launch_bounds__(128) void k_gather(
    const float* __restrict__ h, const float* __restrict__ bg,
    const int* __restrict__ deg, const unsigned int* __restrict__ bmp,
    float* __restrict__ tmp)
{
    __shared__ int list[1024];
    __shared__ float nrm[1024];
    __shared__ int scnt;
    const int tgt = blockIdx.x, b = blockIdx.y, t = threadIdx.x;
    if (t < 32) {
        unsigned word = bmp[((size_t)b * NN + tgt) * 32 + t];
        int pc = __popc(word);
        int pre = pc;
        #pragma unroll
        for (int d = 1; d < 32; d <<= 1) {
            int o = __shfl_up(pre, d, 32);
            if (t >= d) pre += o;
        }
        if (t == 31) scnt = pre;
        int idx = pre - pc;
        while (word) {
            int s = __ffs(word) - 1;
            word &= word - 1;
            list[idx++] = t * 32 + s;
        }
    }
    __syncthreads();
    const int cnt = scnt;
    for (int e = t; e < cnt; e += 128)
        nrm[e] = rsqrtf((float)(deg[b * NN + list[e]] + 2));
    __syncthreads();
    const int f = t;
    float dt = rsqrtf((float)(deg[b * NN + tgt] + 2));
    float acc = 2.0f * dt * h[((size_t)b * NN + tgt) * NF + f];
    for (int e = 0; e < cnt; ++e) {
        int src = list[e];
        acc += h[((size_t)b * NN + src) * NF + f] * nrm[e];
    }
    tmp[((size_t)b * NN + tgt) * NF + f] = bg[f] + dt * acc;
}

// [b][n][f] -> [b][f][n]. grid (32, 4, 32), block 256.
__global__ __launch_bounds__(256) void k_transpose(const float* __restrict__ tmp,
                                                   float* __restrict__ out)
{
    __shared__ float tile[32][33];
    const int t = threadIdx.x;
    const int n0 = blockIdx.x * 32, f0 = blockIdx.y * 32, b = blockIdx.z;
    const int c = t & 31, rb = t >> 5;
    #pragma unroll
    for (int i = 0; i < 4; ++i) {
        int r = rb + i * 8;
        tile[r][c] = tmp[((size_t)b * NN + n0 + r) * NF + f0 + c];
    }
    __syncthreads();
    #pragma unroll
    for (int i = 0; i < 4; ++i) {
        int r = rb + i * 8;
        out[((size_t)b * NF + f0 + r) * NN + n0 + c] = tile[c][r];
    }
}

extern "C" void kernel_launch(void* const* d_in, const int* in_sizes, int n_in,
                              void* d_out, int out_size, void* d_ws, size_t ws_size,
                              hipStream_t stream)
{
    const float* x  = (const float*)d_in[0];
    const float* Wq = (const float*)d_in[1];
    const float* bq = (const float*)d_in[2];
    const float* Wk = (const float*)d_in[3];
    const float* bk = (const float*)d_in[4];
    const float* Wg = (const float*)d_in[5];
    const float* bg = (const float*)d_in[6];
    float* out = (float*)d_out;
    char* ws = (char*)d_ws;

    unsigned short* qh = (unsigned short*)(ws + OFF_QH);
    unsigned short* ql = (unsigned short*)(ws + OFF_QL);
    unsigned short* kh = (unsigned short*)(ws + OFF_KH);
    unsigned short* kl = (unsigned short*)(ws + OFF_KL);
    float*          h   = (float*)(ws + OFF_H);
    int*            deg = (int*)(ws + OFF_DEG);
    unsigned int*   bmp = (unsigned int*)(ws + OFF_BMP);
    int*            wlc = (int*)(ws + OFF_WL);
    int*            wl  = wlc + 1;
    int*            tpk = (int*)(ws + OFF_TOPK);
    double*         Wq64 = (double*)(ws + OFF_W64);
    double*         Wk64 = Wq64 + 8192;
    double*         qT64 = (double*)(ws + OFF_QT64);
    double*         kT64 = (double*)(ws + OFF_KT64);
    float*          tmp  = (float*)(ws + OFF_TMP);

    k_upcast<<<32, 256, 0, stream>>>(Wq, Wk, Wq64, Wk64);
    // zero range: deg + bmp + wl_cnt = 4,325,392 B = 270337 uint4 (done inside k_prep)
    k_prep<<<dim3(16, 2, 32), 256, 0, stream>>>(x, bq, bk, Wq64, Wk64, Wg,
                                                qh, ql, kh, kl, qT64, kT64, h,
                                                (uint4*)(ws + OFF_DEG), 270337);
    k_score<<<dim3(64, 32), 512, 0, stream>>>(qh, ql, kh, kl, bk, deg, bmp, tpk, wlc, wl);
    k_repair<<<1024, 64, 0, stream>>>(qT64, kT64, tpk, wlc, wl, deg, bmp);
    k_gather<<<dim3(1024, 32), 128, 0, stream>>>(h, bg, deg, bmp, tmp);
    k_transpose<<<dim3(32, 4, 32), 256, 0, stream>>>(tmp, out);
}